// Round 19
// baseline (130.234 us; speedup 1.0000x reference)
//
#include <hip/hip_runtime.h>
#include <hip/hip_bf16.h>

#define H_DIM 1024
#define NHEAD 16
#define HDIM  64
#define BATCH 2
#define SEQ   2048
#define MTOT  (BATCH*SEQ)   // 4096
#define LOG2E 1.4426950408889634f

typedef _Float16 f16x8 __attribute__((ext_vector_type(8)));
typedef float  f32x4  __attribute__((ext_vector_type(4)));
typedef float  f32x16 __attribute__((ext_vector_type(16)));
typedef short  short8 __attribute__((ext_vector_type(8)));
typedef unsigned uint2v __attribute__((ext_vector_type(2)));
typedef unsigned short u16;

static __device__ __forceinline__ u16 f2h(float f) {   // RNE fp32->fp16
  _Float16 h = (_Float16)f;
  return __builtin_bit_cast(u16, h);
}
static __device__ __forceinline__ float h2f(unsigned bits) {
  return (float)__builtin_bit_cast(_Float16, (u16)(bits & 0xffffu));
}

// async global->LDS, 16B per lane. LDS dest = wave-uniform base + lane*16.
static __device__ __forceinline__ void load_lds16(const void* g, void* l) {
  __builtin_amdgcn_global_load_lds(
      (const __attribute__((address_space(1))) unsigned int*)g,
      (__attribute__((address_space(3))) unsigned int*)l, 16, 0, 0);
}

// ---------------------------------------------------------------------------
// All fp32->fp16 conversions in ONE dispatch.
// ---------------------------------------------------------------------------
#define N8X (MTOT * H_DIM / 8)          // 524288
#define N8W (H_DIM * H_DIM / 8)         // 131072

__global__ __launch_bounds__(256) void conv_all(
    const float* __restrict__ x,  const float* __restrict__ Wq,
    const float* __restrict__ Wk, const float* __restrict__ Wv,
    const float* __restrict__ Wo,
    u16* __restrict__ xb, u16* __restrict__ W3, u16* __restrict__ Wo16) {
  int gi = blockIdx.x * 256 + threadIdx.x;
  const float* src;
  u16* dst;
  int ci;
  if (gi < N8X) {
    src = x; dst = xb; ci = gi;
  } else {
    int j = gi - N8X;
    int which = j >> 17;           // /131072
    ci = j & (N8W - 1);
    src = which == 0 ? Wq : (which == 1 ? Wk : (which == 2 ? Wv : Wo));
    dst = which < 3 ? W3 + (size_t)which * (N8W * 8) : Wo16;
  }
  float4 a = ((const float4*)src)[ci * 2];
  float4 b = ((const float4*)src)[ci * 2 + 1];
  union { u16 u[8]; short8 s; } r;
  r.u[0] = f2h(a.x); r.u[1] = f2h(a.y); r.u[2] = f2h(a.z); r.u[3] = f2h(a.w);
  r.u[4] = f2h(b.x); r.u[5] = f2h(b.y); r.u[6] = f2h(b.z); r.u[7] = f2h(b.w);
  *(short8*)&dst[ci * 8] = r.s;
}

// ---------------------------------------------------------------------------
// QKV fused GEMM (m97 structure), fp16 MFMA. M=4096, N=3072, K=1024.
// ---------------------------------------------------------------------------
#define BK 32

__global__ __launch_bounds__(256) void gemm_qkv(
    const u16* __restrict__ Xb, const u16* __restrict__ W3,
    const float* __restrict__ bq, const float* __restrict__ bk2,
    const float* __restrict__ bv,
    u16* __restrict__ qp, u16* __restrict__ kp, u16* __restrict__ vp) {
  __shared__ __align__(16) u16 Al[128 * BK];
  __shared__ __align__(16) u16 Bl[128 * BK];
  const int tid = threadIdx.x;
  const int w = tid >> 6, l = tid & 63, lg = l >> 4, lc = l & 15;
  const int wr = w >> 1, wc = w & 1;
  const int m0 = blockIdx.y * 128, n0 = blockIdx.x * 128;
  const int sr = w * 16 + (l >> 2);
  const int sc = (l & 3) * 8;

  f32x4 acc[4][4];
#pragma unroll
  for (int i = 0; i < 4; i++)
#pragma unroll
    for (int j = 0; j < 4; j++) acc[i][j] = (f32x4){0.f, 0.f, 0.f, 0.f};

  for (int k0 = 0; k0 < H_DIM; k0 += BK) {
    __syncthreads();
    load_lds16(&Xb[(size_t)(m0 + sr) * H_DIM + k0 + sc],      &Al[w * 512]);
    load_lds16(&Xb[(size_t)(m0 + 64 + sr) * H_DIM + k0 + sc], &Al[2048 + w * 512]);
    load_lds16(&W3[(size_t)(n0 + sr) * H_DIM + k0 + sc],      &Bl[w * 512]);
    load_lds16(&W3[(size_t)(n0 + 64 + sr) * H_DIM + k0 + sc], &Bl[2048 + w * 512]);
    __syncthreads();

    f16x8 af[4], bfr[4];
#pragma unroll
    for (int mi = 0; mi < 4; mi++)
      af[mi] = *(const f16x8*)&Al[(wr * 64 + mi * 16 + lc) * BK + lg * 8];
#pragma unroll
    for (int nj = 0; nj < 4; nj++)
      bfr[nj] = *(const f16x8*)&Bl[(wc * 64 + nj * 16 + lc) * BK + lg * 8];
#pragma unroll
    for (int mi = 0; mi < 4; mi++)
#pragma unroll
      for (int nj = 0; nj < 4; nj++)
        acc[mi][nj] = __builtin_amdgcn_mfma_f32_16x16x32_f16(af[mi], bfr[nj],
                                                             acc[mi][nj], 0, 0, 0);
  }

  const int np = n0 >> 10;
  u16* outp = np == 0 ? qp : (np == 1 ? kp : vp);
  const float* bias = np == 0 ? bq : (np == 1 ? bk2 : bv);
  const float scale = np == 0 ? (0.125f * LOG2E) : 1.0f;
  const int nc0 = (n0 & 1023) + wc * 64;
  float bvals[4];
#pragma unroll
  for (int nj = 0; nj < 4; nj++) bvals[nj] = bias[nc0 + nj * 16 + lc];
#pragma unroll
  for (int mi = 0; mi < 4; mi++)
#pragma unroll
    for (int nj = 0; nj < 4; nj++)
#pragma unroll
      for (int r = 0; r < 4; r++) {
        int row = m0 + wr * 64 + mi * 16 + lg * 4 + r;
        outp[(size_t)row * 1024 + nc0 + nj * 16 + lc] =
            f2h((acc[mi][nj][r] + bvals[nj]) * scale);
      }
}

// ---------------------------------------------------------------------------
// O-projection, fp16: out = ctx @ Wo^T + bias, fp32 out.
// 128(M)x64(N) tile -> 512 blocks = 2 blocks/CU (r18 committed).
// ---------------------------------------------------------------------------
__global__ __launch_bounds__(256) void gemm_oproj(
    const u16* __restrict__ A16, const u16* __restrict__ B16,
    const float* __restrict__ bias, float* __restrict__ out) {
  __shared__ __align__(16) u16 Al[128 * BK];   // 8KB
  __shared__ __align__(16) u16 Bl[64 * BK];    // 4KB
  const int tid = threadIdx.x;
  const int w = tid >> 6, l = tid & 63, lg = l >> 4, lc = l & 15;
  const int m0 = blockIdx.y * 128, n0 = blockIdx.x * 64;
  const int sra = tid >> 2, sca = (tid & 3) * 8;
  const int srb = (tid >> 2) & 63;

  f32x4 acc[2][4];
#pragma unroll
  for (int i = 0; i < 2; i++)
#pragma unroll
    for (int j = 0; j < 4; j++) acc[i][j] = (f32x4){0.f, 0.f, 0.f, 0.f};

  for (int k0 = 0; k0 < H_DIM; k0 += BK) {
    __syncthreads();
    load_lds16(&A16[(size_t)(m0 + sra) * H_DIM + k0 + sca],      &Al[w * 512]);
    load_lds16(&A16[(size_t)(m0 + 64 + sra) * H_DIM + k0 + sca], &Al[2048 + w * 512]);
    load_lds16(&B16[(size_t)(n0 + srb) * H_DIM + k0 + sca],      &Bl[w * 512]);
    __syncthreads();

    f16x8 af[2], bfr[4];
#pragma unroll
    for (int mi = 0; mi < 2; mi++)
      af[mi] = *(const f16x8*)&Al[(w * 32 + mi * 16 + lc) * BK + lg * 8];
#pragma unroll
    for (int nj = 0; nj < 4; nj++)
      bfr[nj] = *(const f16x8*)&Bl[(nj * 16 + lc) * BK + lg * 8];
#pragma unroll
    for (int mi = 0; mi < 2; mi++)
#pragma unroll
      for (int nj = 0; nj < 4; nj++)
        acc[mi][nj] = __builtin_amdgcn_mfma_f32_16x16x32_f16(af[mi], bfr[nj],
                                                             acc[mi][nj], 0, 0, 0);
  }

  float bvals[4];
#pragma unroll
  for (int nj = 0; nj < 4; nj++) bvals[nj] = bias[n0 + nj * 16 + lc];
#pragma unroll
  for (int mi = 0; mi < 2; mi++)
#pragma unroll
    for (int nj = 0; nj < 4; nj++)
#pragma unroll
      for (int r = 0; r < 4; r++) {
        int row = m0 + w * 32 + mi * 16 + lg * 4 + r;
        out[(size_t)row * 1024 + n0 + nj * 16 + lc] = acc[mi][nj][r] + bvals[nj];
      }
}

// ---------------------------------------------------------------------------
// Flash attention v12: r17 structure (8-wave block, 2 KV halves, in-block
// combine) with K REG-STAGED like V. The r17 flaw: K's global_load_lds was
// issued immediately before the barrier that drains vmcnt(0), exposing its
// full latency every tile. Now K(t+1) loads into 2x uint4 registers right
// after tile t becomes visible -> a full compute phase to land; the barrier
// drain then waits on already-complete loads. LDS single-buffered (32 KB).
// ---------------------------------------------------------------------------
#define KTILES 16

__global__ __launch_bounds__(512, 2) void attn_mfma12(
    const u16* __restrict__ q, const u16* __restrict__ k,
    const u16* __restrict__ v, u16* __restrict__ ctx) {
  __shared__ __align__(16) u16 Ks[2][64 * 64];   // 16KB (also ExO in epilogue)
  __shared__ __align__(16) u16 Vt[2][64 * 64];   // 16KB (also ExL in epilogue)

  const int tid = threadIdx.x;
  const int w8 = tid >> 6;            // 0..7
  const int half = w8 >> 2;           // KV half
  const int w = w8 & 3;               // wave within half
  const int l = tid & 63;
  const int l31 = l & 31, l5 = l >> 5;
  const int ht = tid & 255;           // thread within half
  // XCD swizzle (bijective, 512 wgs)
  const int wg = (blockIdx.x & 7) * 64 + (blockIdx.x >> 3);
  const int qt = wg & 15;
  const int h  = (wg >> 4) & 15;
  const int b  = wg >> 8;
  const size_t row0 = (size_t)b * SEQ;
  const int grow = qt * 128 + w * 32 + l31;

  // Q B-frags: col=q=l31, k(d) = dc*16 + 8*l5 + j
  f16x8 qf[4];
  {
    const u16* qp = q + (row0 + grow) * H_DIM + h * HDIM + 8 * l5;
#pragma unroll
    for (int dc = 0; dc < 4; dc++)
      qf[dc] = *(const f16x8*)(qp + dc * 16);
  }

  // K staging (reg-staged): thread ht owns chunks ht, ht+256 of the
  // swizzled-linear Ks image: chunk c -> (key=c>>3, dchunk=(c&7)^((c>>3)&7)).
  const int c1 = ht + 256;
  const u16* ksrc0 = k + (row0 + half * 1024 + (ht >> 3)) * H_DIM + h * HDIM
                       + ((ht & 7) ^ ((ht >> 3) & 7)) * 8;
  const u16* ksrc1 = k + (row0 + half * 1024 + (c1 >> 3)) * H_DIM + h * HDIM
                       + ((c1 & 7) ^ ((c1 >> 3) & 7)) * 8;

  // V staging: lane owns d = ht&63, key-octets ko, ko+4 (transposed loads).
  const int vd = ht & 63, ko = ht >> 6;
  const u16* vsrc = v + (row0 + half * 1024 + ko * 8) * H_DIM + h * HDIM + vd;
  const int vwo0 = vd * 64 + ((ko)     ^ (vd & 7)) * 8;
  const int vwo1 = vd * 64 + ((ko + 4) ^ (vd & 7)) * 8;

  // ---- prologue: tile 0 into registers ----
  uint4 rK0 = *(const uint4*)ksrc0;
  uint4 rK1 = *(const uint4*)ksrc1;
  uint4 rV0, rV1;
  {
    unsigned a0 = vsrc[0 * H_DIM], a1 = vsrc[1 * H_DIM];
    unsigned a2 = vsrc[2 * H_DIM], a3 = vsrc[3 * H_DIM];
    unsigned a4 = vsrc[4 * H_DIM], a5 = vsrc[5 * H_DIM];
    unsigned a6 = vsrc[6 * H_DIM], a7 = vsrc[7 * H_DIM];
    rV0.x = a0 | (a1 << 16); rV0.y = a2 | (a3 << 16);
    rV0.z = a4 | (a5 << 16); rV0.w = a6 | (a7 << 16);
    const u16* v2 = vsrc + 32 * H_DIM;
    unsigned b0 = v2[0 * H_DIM], b1 = v2[1 * H_DIM];
    unsigned b2 = v2[2 * H_DIM], b3 = v2[3 * H_DIM];
    unsigned b4 = v2[4 * H_DIM], b5 = v2[5 * H_DIM];
    unsigned b6 = v2[6 * H_DIM], b7 = v2[7 * H_DIM];
    rV1.x = b0 | (b1 << 16); rV1.y = b2 | (b3 << 16);
    rV1.z = b4 | (b5 << 16); rV1.w = b6 | (b7 << 16);
  }

  f32x16 Oacc[2];
#pragma unroll
  for (int i = 0; i < 2; i++)
#pragma unroll
    for (int r = 0; r < 16; r++) Oacc[i][r] = 0.f;
  float lS = 0.f;

  for (int t = 0; t < KTILES; ++t) {
    __syncthreads();                       // prev tile reads done; prefetch landed
    *(uint4*)&Ks[half][ht * 8] = rK0;      // linear chunk image (conflict-free)
    *(uint4*)&Ks[half][2048 + ht * 8] = rK1;
    *(uint4*)&Vt[half][vwo0] = rV0;
    *(uint4*)&Vt[half][vwo1] = rV1;
    __syncthreads();                       // K+V visible

    if (t + 1 < KTILES) {                  // issue next-tile loads; they get a
      ksrc0 += 64 * H_DIM;                 // full compute phase to land
      ksrc1 += 64 * H_DIM;
      rK0 = *(const uint4*)ksrc0;
      rK1 = *(const uint4*)ksrc1;
      vsrc += 64 * H_DIM;
      unsigned a0 = vsrc[0 * H_DIM], a1 = vsrc[1 * H_DIM];
      unsigned a2 = vsrc[2 * H_DIM], a3 = vsrc[3 * H_DIM];
      unsigned a4 = vsrc[4 * H_DIM], a5 = vsrc[5 * H_DIM];
      unsigned a6 = vsrc[6 * H_DIM], a7 = vsrc[7 * H_DIM];
      rV0.x = a0 | (a1 << 16); rV0.y = a2 | (a3 << 16);
      rV0.z = a4 | (a5 << 16); rV0.w = a6 | (a7 << 16);
      const u16* v2 = vsrc + 32 * H_DIM;
      unsigned b0 = v2[0 * H_DIM], b1 = v2[1 * H_DIM];
      unsigned b2 = v2[2 * H_DIM], b3 = v2[3 * H_DIM];
      unsigned b4 = v2[4 * H_DIM], b5 = v2[5 * H_DIM];
      unsigned b6 = v2[6 * H_DIM], b7 = v2[7 * H_DIM];
      rV1.x = b0 | (b1 << 16); rV1.y = b2 | (b3 << 16);
      rV1.z = b4 | (b5 << 16); rV1.w = b6 | (b7 << 16);
    }

    // ---- QK + exp + pack ----
    unsigned pw[2][4][2];
    float ps = 0.f;
#pragma unroll
    for (int kc = 0; kc < 2; kc++) {
      f32x16 s;
#pragma unroll
      for (int r = 0; r < 16; r++) s[r] = 0.f;
      const int key = kc * 32 + l31;
      const int rowb = key * 64, keyx = key & 7;
#pragma unroll
      for (int dc = 0; dc < 4; dc++) {
        f16x8 af = *(const f16x8*)&Ks[half][rowb + (((dc << 1) + l5) ^ keyx) * 8];
        s = __builtin_amdgcn_mfma_f32_32x32x16_f16(af, qf[dc], s, 0, 0, 0);
      }
#pragma unroll
      for (int rh = 0; rh < 4; rh++)
#pragma unroll
        for (int k1 = 0; k1 < 2; k1++) {
          float e0 = exp2f(s[4 * rh + 2 * k1]);
          float e1 = exp2f(s[4 * rh + 2 * k1 + 1]);
          ps += e0 + e1;
          pw[kc][rh][k1] = __builtin_bit_cast(
              unsigned, __builtin_amdgcn_cvt_pkrtz(e0, e1));
        }
    }
    lS += ps;

    // ---- PV: B-frags via permlane32_swap, A-frags from Vt ----
#pragma unroll
    for (int kcc = 0; kcc < 4; kcc++) {
      union { unsigned u[4]; f16x8 v8; } bf;
      const int kcs = kcc >> 1, rhA = (kcc & 1) << 1;
#pragma unroll
      for (int k1 = 0; k1 < 2; k1++) {
        uint2v xy = __builtin_amdgcn_permlane32_swap(
            pw[kcs][rhA][k1], pw[kcs][rhA + 1][k1], false, false);
        bf.u[k1] = xy.x;
        bf.u[2 + k1] = xy.y;
      }
#pragma unroll
      for (int dc2 = 0; dc2 < 2; dc2++) {
        const int d = dc2 * 32 + l31;
        f16x8 vf = *(const f16x8*)&Vt[half][d * 64 + (((kcc << 1) + l5) ^ (d & 7)) * 8];
        Oacc[dc2] = __builtin_amdgcn_mfma_f32_32x32x16_f16(vf, bf.v8,
                                                           Oacc[dc2], 0, 0, 0);
      }
    }
  }

  // ---- epilogue: in-block combine of the two halves ----
  __syncthreads();
  lS += __shfl_xor(lS, 32);
  const int qloc = w * 32 + l31;
  u16* ExO = &Ks[0][0];
  float* ExL = (float*)&Vt[0][0];

  if (half == 1) {
#pragma unroll
    for (int dc2 = 0; dc2 < 2; dc2++)
#pragma unroll
      for (int rh = 0; rh < 4; rh++) {
        uint2 pd;
        pd.x = __builtin_bit_cast(unsigned, __builtin_amdgcn_cvt_pkrtz(
            Oacc[dc2][4 * rh + 0], Oacc[dc2][4 * rh + 1]));
        pd.y = __builtin_bit_cast(unsigned, __builtin_amdgcn_cvt_pkrtz(
            Oacc[dc2][4 * rh + 2], Oacc[dc2][4 * rh + 3]));
        const int chunk = dc2 * 4 + rh;
        *(uint2*)&ExO[qloc * 64 + ((chunk ^ (qloc & 7)) << 3) + 4 * l5] = pd;
      }
    if (l < 32) ExL[qloc] = lS;
  }
  __syncthreads();
  if (half == 0) {
    float inv = 1.f / (lS + ExL[qloc]);
    const size_t obase = (row0 + grow) * H_DIM + h * HDIM;
#pragma unroll
    for (int dc2 = 0; dc2 < 2; dc2++)
#pragma unroll
      for (int rh = 0; rh < 4; rh++) {
        const int chunk = dc2 * 4 + rh;
        uint2 t = *(const uint2*)&ExO[qloc * 64 + ((chunk ^ (qloc & 7)) << 3) + 4 * l5];
        float o0 = (Oacc[dc2][4 * rh + 0] + h2f(t.x)) * inv;
        float o1 = (Oacc[dc2][4 * rh + 1] + h2f(t.x >> 16)) * inv;
        float o2 = (Oacc[dc2][4 * rh + 2] + h2f(t.y)) * inv;
        float o3 = (Oacc[dc2][4 * rh + 3] + h2f(t.y >> 16)) * inv;
        uint2 pd;
        pd.x = __builtin_bit_cast(unsigned, __builtin_amdgcn_cvt_pkrtz(o0, o1));
        pd.y = __builtin_bit_cast(unsigned, __builtin_amdgcn_cvt_pkrtz(o2, o3));
        *(uint2*)&ctx[obase + dc2 * 32 + 8 * rh + 4 * l5] = pd;
      }
  }
}

// ---------------------------------------------------------------------------
extern "C" void kernel_launch(void* const* d_in, const int* in_sizes, int n_in,
                              void* d_out, int out_size, void* d_ws, size_t ws_size,
                              hipStream_t stream) {
  const float* x  = (const float*)d_in[0];
  const float* Wq = (const float*)d_in[1];
  const float* bq = (const float*)d_in[2];
  const float* Wk = (const float*)d_in[3];
  const float* bk = (const float*)d_in[4];
  const float* Wv = (const float*)d_in[5];
  const float* bv = (const float*)d_in[6];
  const float* Wo = (const float*)d_in[7];
  const float* bo = (const float*)d_in[8];
  float* out = (float*)d_out;

  const size_t PL = (size_t)MTOT * H_DIM;   // 4M elems
  const size_t WN = (size_t)H_DIM * H_DIM;  // 1M elems
  u16* xb    = (u16*)d_ws;                  // fp16 planes
  u16* W3    = xb + PL;
  u16* qp    = W3 + 3 * WN;
  u16* kp    = qp + PL;
  u16* vp    = kp + PL;
  u16* ctxp  = vp + PL;
  u16* Wo16  = ctxp + PL;

  conv_all<<<(N8X + 4 * N8W) / 256, 256, 0, stream>>>(
      x, Wq, Wk, Wv, Wo, xb, W3, Wo16);

  gemm_qkv<<<dim3(3072 / 128, MTOT / 128), 256, 0, stream>>>(
      xb, W3, bq, bk, bv, qp, kp, vp);

  attn_mfma12<<<dim3(512), 512, 0, stream>>>(qp, kp, vp, ctxp);

  gemm_oproj<<<dim3(1024 / 64, MTOT / 128), 256, 0, stream>>>(
      ctxp, Wo16, bo, out);
}

// Round 20
// 128.648 us; speedup vs baseline: 1.0123x; 1.0123x over previous
//
#include <hip/hip_runtime.h>
#include <hip/hip_bf16.h>

#define H_DIM 1024
#define NHEAD 16
#define HDIM  64
#define BATCH 2
#define SEQ   2048
#define MTOT  (BATCH*SEQ)   // 4096
#define LOG2E 1.4426950408889634f

typedef _Float16 f16x8 __attribute__((ext_vector_type(8)));
typedef float  f32x4  __attribute__((ext_vector_type(4)));
typedef float  f32x16 __attribute__((ext_vector_type(16)));
typedef short  short8 __attribute__((ext_vector_type(8)));
typedef unsigned uint2v __attribute__((ext_vector_type(2)));
typedef unsigned short u16;

static __device__ __forceinline__ u16 f2h(float f) {   // RNE fp32->fp16
  _Float16 h = (_Float16)f;
  return __builtin_bit_cast(u16, h);
}
static __device__ __forceinline__ float h2f(unsigned bits) {
  return (float)__builtin_bit_cast(_Float16, (u16)(bits & 0xffffu));
}

// async global->LDS, 16B per lane. LDS dest = wave-uniform base + lane*16.
static __device__ __forceinline__ void load_lds16(const void* g, void* l) {
  __builtin_amdgcn_global_load_lds(
      (const __attribute__((address_space(1))) unsigned int*)g,
      (__attribute__((address_space(3))) unsigned int*)l, 16, 0, 0);
}

// ---------------------------------------------------------------------------
// All fp32->fp16 conversions in ONE dispatch.
// ---------------------------------------------------------------------------
#define N8X (MTOT * H_DIM / 8)          // 524288
#define N8W (H_DIM * H_DIM / 8)         // 131072

__global__ __launch_bounds__(256) void conv_all(
    const float* __restrict__ x,  const float* __restrict__ Wq,
    const float* __restrict__ Wk, const float* __restrict__ Wv,
    const float* __restrict__ Wo,
    u16* __restrict__ xb, u16* __restrict__ W3, u16* __restrict__ Wo16) {
  int gi = blockIdx.x * 256 + threadIdx.x;
  const float* src;
  u16* dst;
  int ci;
  if (gi < N8X) {
    src = x; dst = xb; ci = gi;
  } else {
    int j = gi - N8X;
    int which = j >> 17;           // /131072
    ci = j & (N8W - 1);
    src = which == 0 ? Wq : (which == 1 ? Wk : (which == 2 ? Wv : Wo));
    dst = which < 3 ? W3 + (size_t)which * (N8W * 8) : Wo16;
  }
  float4 a = ((const float4*)src)[ci * 2];
  float4 b = ((const float4*)src)[ci * 2 + 1];
  union { u16 u[8]; short8 s; } r;
  r.u[0] = f2h(a.x); r.u[1] = f2h(a.y); r.u[2] = f2h(a.z); r.u[3] = f2h(a.w);
  r.u[4] = f2h(b.x); r.u[5] = f2h(b.y); r.u[6] = f2h(b.z); r.u[7] = f2h(b.w);
  *(short8*)&dst[ci * 8] = r.s;
}

// ---------------------------------------------------------------------------
// QKV fused GEMM (m97 structure), fp16 MFMA. M=4096, N=3072, K=1024.
// ---------------------------------------------------------------------------
#define BK 32

__global__ __launch_bounds__(256) void gemm_qkv(
    const u16* __restrict__ Xb, const u16* __restrict__ W3,
    const float* __restrict__ bq, const float* __restrict__ bk2,
    const float* __restrict__ bv,
    u16* __restrict__ qp, u16* __restrict__ kp, u16* __restrict__ vp) {
  __shared__ __align__(16) u16 Al[128 * BK];
  __shared__ __align__(16) u16 Bl[128 * BK];
  const int tid = threadIdx.x;
  const int w = tid >> 6, l = tid & 63, lg = l >> 4, lc = l & 15;
  const int wr = w >> 1, wc = w & 1;
  const int m0 = blockIdx.y * 128, n0 = blockIdx.x * 128;
  const int sr = w * 16 + (l >> 2);
  const int sc = (l & 3) * 8;

  f32x4 acc[4][4];
#pragma unroll
  for (int i = 0; i < 4; i++)
#pragma unroll
    for (int j = 0; j < 4; j++) acc[i][j] = (f32x4){0.f, 0.f, 0.f, 0.f};

  for (int k0 = 0; k0 < H_DIM; k0 += BK) {
    __syncthreads();
    load_lds16(&Xb[(size_t)(m0 + sr) * H_DIM + k0 + sc],      &Al[w * 512]);
    load_lds16(&Xb[(size_t)(m0 + 64 + sr) * H_DIM + k0 + sc], &Al[2048 + w * 512]);
    load_lds16(&W3[(size_t)(n0 + sr) * H_DIM + k0 + sc],      &Bl[w * 512]);
    load_lds16(&W3[(size_t)(n0 + 64 + sr) * H_DIM + k0 + sc], &Bl[2048 + w * 512]);
    __syncthreads();

    f16x8 af[4], bfr[4];
#pragma unroll
    for (int mi = 0; mi < 4; mi++)
      af[mi] = *(const f16x8*)&Al[(wr * 64 + mi * 16 + lc) * BK + lg * 8];
#pragma unroll
    for (int nj = 0; nj < 4; nj++)
      bfr[nj] = *(const f16x8*)&Bl[(wc * 64 + nj * 16 + lc) * BK + lg * 8];
#pragma unroll
    for (int mi = 0; mi < 4; mi++)
#pragma unroll
      for (int nj = 0; nj < 4; nj++)
        acc[mi][nj] = __builtin_amdgcn_mfma_f32_16x16x32_f16(af[mi], bfr[nj],
                                                             acc[mi][nj], 0, 0, 0);
  }

  const int np = n0 >> 10;
  u16* outp = np == 0 ? qp : (np == 1 ? kp : vp);
  const float* bias = np == 0 ? bq : (np == 1 ? bk2 : bv);
  const float scale = np == 0 ? (0.125f * LOG2E) : 1.0f;
  const int nc0 = (n0 & 1023) + wc * 64;
  float bvals[4];
#pragma unroll
  for (int nj = 0; nj < 4; nj++) bvals[nj] = bias[nc0 + nj * 16 + lc];
#pragma unroll
  for (int mi = 0; mi < 4; mi++)
#pragma unroll
    for (int nj = 0; nj < 4; nj++)
#pragma unroll
      for (int r = 0; r < 4; r++) {
        int row = m0 + wr * 64 + mi * 16 + lg * 4 + r;
        outp[(size_t)row * 1024 + nc0 + nj * 16 + lc] =
            f2h((acc[mi][nj][r] + bvals[nj]) * scale);
      }
}

// ---------------------------------------------------------------------------
// O-projection, fp16: out = ctx @ Wo^T + bias, fp32 out.
// 128(M)x64(N) tile -> 512 blocks = 2 blocks/CU (r18 committed).
// ---------------------------------------------------------------------------
__global__ __launch_bounds__(256) void gemm_oproj(
    const u16* __restrict__ A16, const u16* __restrict__ B16,
    const float* __restrict__ bias, float* __restrict__ out) {
  __shared__ __align__(16) u16 Al[128 * BK];   // 8KB
  __shared__ __align__(16) u16 Bl[64 * BK];    // 4KB
  const int tid = threadIdx.x;
  const int w = tid >> 6, l = tid & 63, lg = l >> 4, lc = l & 15;
  const int m0 = blockIdx.y * 128, n0 = blockIdx.x * 64;
  const int sra = tid >> 2, sca = (tid & 3) * 8;
  const int srb = (tid >> 2) & 63;

  f32x4 acc[2][4];
#pragma unroll
  for (int i = 0; i < 2; i++)
#pragma unroll
    for (int j = 0; j < 4; j++) acc[i][j] = (f32x4){0.f, 0.f, 0.f, 0.f};

  for (int k0 = 0; k0 < H_DIM; k0 += BK) {
    __syncthreads();
    load_lds16(&A16[(size_t)(m0 + sra) * H_DIM + k0 + sca],      &Al[w * 512]);
    load_lds16(&A16[(size_t)(m0 + 64 + sra) * H_DIM + k0 + sca], &Al[2048 + w * 512]);
    load_lds16(&B16[(size_t)(n0 + srb) * H_DIM + k0 + sca],      &Bl[w * 512]);
    __syncthreads();

    f16x8 af[2], bfr[4];
#pragma unroll
    for (int mi = 0; mi < 2; mi++)
      af[mi] = *(const f16x8*)&Al[(w * 32 + mi * 16 + lc) * BK + lg * 8];
#pragma unroll
    for (int nj = 0; nj < 4; nj++)
      bfr[nj] = *(const f16x8*)&Bl[(nj * 16 + lc) * BK + lg * 8];
#pragma unroll
    for (int mi = 0; mi < 2; mi++)
#pragma unroll
      for (int nj = 0; nj < 4; nj++)
        acc[mi][nj] = __builtin_amdgcn_mfma_f32_16x16x32_f16(af[mi], bfr[nj],
                                                             acc[mi][nj], 0, 0, 0);
  }

  float bvals[4];
#pragma unroll
  for (int nj = 0; nj < 4; nj++) bvals[nj] = bias[n0 + nj * 16 + lc];
#pragma unroll
  for (int mi = 0; mi < 2; mi++)
#pragma unroll
    for (int nj = 0; nj < 4; nj++)
#pragma unroll
      for (int r = 0; r < 4; r++) {
        int row = m0 + w * 32 + mi * 16 + lg * 4 + r;
        out[(size_t)row * 1024 + n0 + nj * 16 + lc] = acc[mi][nj][r] + bvals[nj];
      }
}

// ---------------------------------------------------------------------------
// Flash attention v11 (r17/r18 committed): r10 main loop x2 halves in ONE
// 512-thread block; in-block combine epilogue. 32 q/wave (32x32x16 MFMA),
// P in-register via permlane32_swap, no-max log2 softmax, chunk-XOR LDS.
// ---------------------------------------------------------------------------
#define KTILES 16

__global__ __launch_bounds__(512, 2) void attn_mfma11(
    const u16* __restrict__ q, const u16* __restrict__ k,
    const u16* __restrict__ v, u16* __restrict__ ctx) {
  __shared__ __align__(16) u16 Ks[2][64 * 64];   // 16KB (also ExO in epilogue)
  __shared__ __align__(16) u16 Vt[2][64 * 64];   // 16KB (also ExL in epilogue)

  const int tid = threadIdx.x;
  const int w8 = tid >> 6;            // 0..7
  const int half = w8 >> 2;           // KV half
  const int w = w8 & 3;               // wave within half
  const int l = tid & 63;
  const int l31 = l & 31, l5 = l >> 5;
  const int ht = tid & 255;           // thread within half
  // XCD swizzle (bijective, 512 wgs)
  const int wg = (blockIdx.x & 7) * 64 + (blockIdx.x >> 3);
  const int qt = wg & 15;
  const int h  = (wg >> 4) & 15;
  const int b  = wg >> 8;
  const size_t row0 = (size_t)b * SEQ;
  const int grow = qt * 128 + w * 32 + l31;

  f16x8 qf[4];
  {
    const u16* qp = q + (row0 + grow) * H_DIM + h * HDIM + 8 * l5;
#pragma unroll
    for (int dc = 0; dc < 4; dc++)
      qf[dc] = *(const f16x8*)(qp + dc * 16);
  }

  const int c1 = ht + 256;
  const u16* ksrc0 = k + (row0 + half * 1024 + (ht >> 3)) * H_DIM + h * HDIM
                       + ((ht & 7) ^ ((ht >> 3) & 7)) * 8;
  const u16* ksrc1 = k + (row0 + half * 1024 + (c1 >> 3)) * H_DIM + h * HDIM
                       + ((c1 & 7) ^ ((c1 >> 3) & 7)) * 8;

  const int vd = ht & 63, ko = ht >> 6;
  const u16* vsrc = v + (row0 + half * 1024 + ko * 8) * H_DIM + h * HDIM + vd;
  const int vwo0 = vd * 64 + ((ko)     ^ (vd & 7)) * 8;
  const int vwo1 = vd * 64 + ((ko + 4) ^ (vd & 7)) * 8;

  uint4 rV0, rV1;
  {
    unsigned a0 = vsrc[0 * H_DIM], a1 = vsrc[1 * H_DIM];
    unsigned a2 = vsrc[2 * H_DIM], a3 = vsrc[3 * H_DIM];
    unsigned a4 = vsrc[4 * H_DIM], a5 = vsrc[5 * H_DIM];
    unsigned a6 = vsrc[6 * H_DIM], a7 = vsrc[7 * H_DIM];
    rV0.x = a0 | (a1 << 16); rV0.y = a2 | (a3 << 16);
    rV0.z = a4 | (a5 << 16); rV0.w = a6 | (a7 << 16);
    const u16* v2 = vsrc + 32 * H_DIM;
    unsigned b0 = v2[0 * H_DIM], b1 = v2[1 * H_DIM];
    unsigned b2 = v2[2 * H_DIM], b3 = v2[3 * H_DIM];
    unsigned b4 = v2[4 * H_DIM], b5 = v2[5 * H_DIM];
    unsigned b6 = v2[6 * H_DIM], b7 = v2[7 * H_DIM];
    rV1.x = b0 | (b1 << 16); rV1.y = b2 | (b3 << 16);
    rV1.z = b4 | (b5 << 16); rV1.w = b6 | (b7 << 16);
  }

  f32x16 Oacc[2];
#pragma unroll
  for (int i = 0; i < 2; i++)
#pragma unroll
    for (int r = 0; r < 16; r++) Oacc[i][r] = 0.f;
  float lS = 0.f;

  for (int t = 0; t < KTILES; ++t) {
    __syncthreads();
    load_lds16(ksrc0, &Ks[half][w * 512]);
    load_lds16(ksrc1, &Ks[half][2048 + w * 512]);
    *(uint4*)&Vt[half][vwo0] = rV0;
    *(uint4*)&Vt[half][vwo1] = rV1;
    __syncthreads();
    ksrc0 += 64 * H_DIM;
    ksrc1 += 64 * H_DIM;

    if (t + 1 < KTILES) {
      vsrc += 64 * H_DIM;
      unsigned a0 = vsrc[0 * H_DIM], a1 = vsrc[1 * H_DIM];
      unsigned a2 = vsrc[2 * H_DIM], a3 = vsrc[3 * H_DIM];
      unsigned a4 = vsrc[4 * H_DIM], a5 = vsrc[5 * H_DIM];
      unsigned a6 = vsrc[6 * H_DIM], a7 = vsrc[7 * H_DIM];
      rV0.x = a0 | (a1 << 16); rV0.y = a2 | (a3 << 16);
      rV0.z = a4 | (a5 << 16); rV0.w = a6 | (a7 << 16);
      const u16* v2 = vsrc + 32 * H_DIM;
      unsigned b0 = v2[0 * H_DIM], b1 = v2[1 * H_DIM];
      unsigned b2 = v2[2 * H_DIM], b3 = v2[3 * H_DIM];
      unsigned b4 = v2[4 * H_DIM], b5 = v2[5 * H_DIM];
      unsigned b6 = v2[6 * H_DIM], b7 = v2[7 * H_DIM];
      rV1.x = b0 | (b1 << 16); rV1.y = b2 | (b3 << 16);
      rV1.z = b4 | (b5 << 16); rV1.w = b6 | (b7 << 16);
    }

    unsigned pw[2][4][2];
    float ps = 0.f;
#pragma unroll
    for (int kc = 0; kc < 2; kc++) {
      f32x16 s;
#pragma unroll
      for (int r = 0; r < 16; r++) s[r] = 0.f;
      const int key = kc * 32 + l31;
      const int rowb = key * 64, keyx = key & 7;
#pragma unroll
      for (int dc = 0; dc < 4; dc++) {
        f16x8 af = *(const f16x8*)&Ks[half][rowb + (((dc << 1) + l5) ^ keyx) * 8];
        s = __builtin_amdgcn_mfma_f32_32x32x16_f16(af, qf[dc], s, 0, 0, 0);
      }
#pragma unroll
      for (int rh = 0; rh < 4; rh++)
#pragma unroll
        for (int k1 = 0; k1 < 2; k1++) {
          float e0 = exp2f(s[4 * rh + 2 * k1]);
          float e1 = exp2f(s[4 * rh + 2 * k1 + 1]);
          ps += e0 + e1;
          pw[kc][rh][k1] = __builtin_bit_cast(
              unsigned, __builtin_amdgcn_cvt_pkrtz(e0, e1));
        }
    }
    lS += ps;

#pragma unroll
    for (int kcc = 0; kcc < 4; kcc++) {
      union { unsigned u[4]; f16x8 v8; } bf;
      const int kcs = kcc >> 1, rhA = (kcc & 1) << 1;
#pragma unroll
      for (int k1 = 0; k1 < 2; k1++) {
        uint2v xy = __builtin_amdgcn_permlane32_swap(
            pw[kcs][rhA][k1], pw[kcs][rhA + 1][k1], false, false);
        bf.u[k1] = xy.x;
        bf.u[2 + k1] = xy.y;
      }
#pragma unroll
      for (int dc2 = 0; dc2 < 2; dc2++) {
        const int d = dc2 * 32 + l31;
        f16x8 vf = *(const f16x8*)&Vt[half][d * 64 + (((kcc << 1) + l5) ^ (d & 7)) * 8];
        Oacc[dc2] = __builtin_amdgcn_mfma_f32_32x32x16_f16(vf, bf.v8,
                                                           Oacc[dc2], 0, 0, 0);
      }
    }
  }

  // ---- epilogue: in-block combine of the two halves ----
  __syncthreads();
  lS += __shfl_xor(lS, 32);
  const int qloc = w * 32 + l31;
  u16* ExO = &Ks[0][0];
  float* ExL = (float*)&Vt[0][0];

  if (half == 1) {
#pragma unroll
    for (int dc2 = 0; dc2 < 2; dc2++)
#pragma unroll
      for (int rh = 0; rh < 4; rh++) {
        uint2 pd;
        pd.x = __builtin_bit_cast(unsigned, __builtin_amdgcn_cvt_pkrtz(
            Oacc[dc2][4 * rh + 0], Oacc[dc2][4 * rh + 1]));
        pd.y = __builtin_bit_cast(unsigned, __builtin_amdgcn_cvt_pkrtz(
            Oacc[dc2][4 * rh + 2], Oacc[dc2][4 * rh + 3]));
        const int chunk = dc2 * 4 + rh;
        *(uint2*)&ExO[qloc * 64 + ((chunk ^ (qloc & 7)) << 3) + 4 * l5] = pd;
      }
    if (l < 32) ExL[qloc] = lS;
  }
  __syncthreads();
  if (half == 0) {
    float inv = 1.f / (lS + ExL[qloc]);
    const size_t obase = (row0 + grow) * H_DIM + h * HDIM;
#pragma unroll
    for (int dc2 = 0; dc2 < 2; dc2++)
#pragma unroll
      for (int rh = 0; rh < 4; rh++) {
        const int chunk = dc2 * 4 + rh;
        uint2 t = *(const uint2*)&ExO[qloc * 64 + ((chunk ^ (qloc & 7)) << 3) + 4 * l5];
        float o0 = (Oacc[dc2][4 * rh + 0] + h2f(t.x)) * inv;
        float o1 = (Oacc[dc2][4 * rh + 1] + h2f(t.x >> 16)) * inv;
        float o2 = (Oacc[dc2][4 * rh + 2] + h2f(t.y)) * inv;
        float o3 = (Oacc[dc2][4 * rh + 3] + h2f(t.y >> 16)) * inv;
        uint2 pd;
        pd.x = __builtin_bit_cast(unsigned, __builtin_amdgcn_cvt_pkrtz(o0, o1));
        pd.y = __builtin_bit_cast(unsigned, __builtin_amdgcn_cvt_pkrtz(o2, o3));
        *(uint2*)&ctx[obase + dc2 * 32 + 8 * rh + 4 * l5] = pd;
      }
  }
}

// ---------------------------------------------------------------------------
extern "C" void kernel_launch(void* const* d_in, const int* in_sizes, int n_in,
                              void* d_out, int out_size, void* d_ws, size_t ws_size,
                              hipStream_t stream) {
  const float* x  = (const float*)d_in[0];
  const float* Wq = (const float*)d_in[1];
  const float* bq = (const float*)d_in[2];
  const float* Wk = (const float*)d_in[3];
  const float* bk = (const float*)d_in[4];
  const float* Wv = (const float*)d_in[5];
  const float* bv = (const float*)d_in[6];
  const float* Wo = (const float*)d_in[7];
  const float* bo = (const float*)d_in[8];
  float* out = (float*)d_out;

  const size_t PL = (size_t)MTOT * H_DIM;   // 4M elems
  const size_t WN = (size_t)H_DIM * H_DIM;  // 1M elems
  u16* xb    = (u16*)d_ws;                  // fp16 planes
  u16* W3    = xb + PL;
  u16* qp    = W3 + 3 * WN;
  u16* kp    = qp + PL;
  u16* vp    = kp + PL;
  u16* ctxp  = vp + PL;
  u16* Wo16  = ctxp + PL;

  conv_all<<<(N8X + 4 * N8W) / 256, 256, 0, stream>>>(
      x, Wq, Wk, Wv, Wo, xb, W3, Wo16);

  gemm_qkv<<<dim3(3072 / 128, MTOT / 128), 256, 0, stream>>>(
      xb, W3, bq, bk, bv, qp, kp, vp);

  attn_mfma11<<<dim3(512), 512, 0, stream>>>(qp, kp, vp, ctxp);

  gemm_oproj<<<dim3(1024 / 64, MTOT / 128), 256, 0, stream>>>(
      ctxp, Wo16, bo, out);
}

// Round 21
// 127.222 us; speedup vs baseline: 1.0237x; 1.0112x over previous
//
#include <hip/hip_runtime.h>
#include <hip/hip_bf16.h>

#define H_DIM 1024
#define NHEAD 16
#define HDIM  64
#define BATCH 2
#define SEQ   2048
#define MTOT  (BATCH*SEQ)   // 4096
#define LOG2E 1.4426950408889634f

typedef _Float16 f16x8 __attribute__((ext_vector_type(8)));
typedef _Float16 f16x2 __attribute__((ext_vector_type(2)));
typedef float  f32x4  __attribute__((ext_vector_type(4)));
typedef float  f32x16 __attribute__((ext_vector_type(16)));
typedef short  short8 __attribute__((ext_vector_type(8)));
typedef unsigned uint2v __attribute__((ext_vector_type(2)));
typedef unsigned short u16;

static __device__ __forceinline__ u16 f2h(float f) {   // RNE fp32->fp16
  _Float16 h = (_Float16)f;
  return __builtin_bit_cast(u16, h);
}
static __device__ __forceinline__ float h2f(unsigned bits) {
  return (float)__builtin_bit_cast(_Float16, (u16)(bits & 0xffffu));
}
static __device__ __forceinline__ f16x2 bch(unsigned u) {
  return __builtin_bit_cast(f16x2, u);
}

// async global->LDS, 16B per lane. LDS dest = wave-uniform base + lane*16.
static __device__ __forceinline__ void load_lds16(const void* g, void* l) {
  __builtin_amdgcn_global_load_lds(
      (const __attribute__((address_space(1))) unsigned int*)g,
      (__attribute__((address_space(3))) unsigned int*)l, 16, 0, 0);
}

// ---------------------------------------------------------------------------
// All fp32->fp16 conversions in ONE dispatch.
// ---------------------------------------------------------------------------
#define N8X (MTOT * H_DIM / 8)          // 524288
#define N8W (H_DIM * H_DIM / 8)         // 131072

__global__ __launch_bounds__(256) void conv_all(
    const float* __restrict__ x,  const float* __restrict__ Wq,
    const float* __restrict__ Wk, const float* __restrict__ Wv,
    const float* __restrict__ Wo,
    u16* __restrict__ xb, u16* __restrict__ W3, u16* __restrict__ Wo16) {
  int gi = blockIdx.x * 256 + threadIdx.x;
  const float* src;
  u16* dst;
  int ci;
  if (gi < N8X) {
    src = x; dst = xb; ci = gi;
  } else {
    int j = gi - N8X;
    int which = j >> 17;           // /131072
    ci = j & (N8W - 1);
    src = which == 0 ? Wq : (which == 1 ? Wk : (which == 2 ? Wv : Wo));
    dst = which < 3 ? W3 + (size_t)which * (N8W * 8) : Wo16;
  }
  float4 a = ((const float4*)src)[ci * 2];
  float4 b = ((const float4*)src)[ci * 2 + 1];
  union { u16 u[8]; short8 s; } r;
  r.u[0] = f2h(a.x); r.u[1] = f2h(a.y); r.u[2] = f2h(a.z); r.u[3] = f2h(a.w);
  r.u[4] = f2h(b.x); r.u[5] = f2h(b.y); r.u[6] = f2h(b.z); r.u[7] = f2h(b.w);
  *(short8*)&dst[ci * 8] = r.s;
}

// ---------------------------------------------------------------------------
// QKV fused GEMM (m97 structure), fp16 MFMA. M=4096, N=3072, K=1024.
// ---------------------------------------------------------------------------
#define BK 32

__global__ __launch_bounds__(256) void gemm_qkv(
    const u16* __restrict__ Xb, const u16* __restrict__ W3,
    const float* __restrict__ bq, const float* __restrict__ bk2,
    const float* __restrict__ bv,
    u16* __restrict__ qp, u16* __restrict__ kp, u16* __restrict__ vp) {
  __shared__ __align__(16) u16 Al[128 * BK];
  __shared__ __align__(16) u16 Bl[128 * BK];
  const int tid = threadIdx.x;
  const int w = tid >> 6, l = tid & 63, lg = l >> 4, lc = l & 15;
  const int wr = w >> 1, wc = w & 1;
  const int m0 = blockIdx.y * 128, n0 = blockIdx.x * 128;
  const int sr = w * 16 + (l >> 2);
  const int sc = (l & 3) * 8;

  f32x4 acc[4][4];
#pragma unroll
  for (int i = 0; i < 4; i++)
#pragma unroll
    for (int j = 0; j < 4; j++) acc[i][j] = (f32x4){0.f, 0.f, 0.f, 0.f};

  for (int k0 = 0; k0 < H_DIM; k0 += BK) {
    __syncthreads();
    load_lds16(&Xb[(size_t)(m0 + sr) * H_DIM + k0 + sc],      &Al[w * 512]);
    load_lds16(&Xb[(size_t)(m0 + 64 + sr) * H_DIM + k0 + sc], &Al[2048 + w * 512]);
    load_lds16(&W3[(size_t)(n0 + sr) * H_DIM + k0 + sc],      &Bl[w * 512]);
    load_lds16(&W3[(size_t)(n0 + 64 + sr) * H_DIM + k0 + sc], &Bl[2048 + w * 512]);
    __syncthreads();

    f16x8 af[4], bfr[4];
#pragma unroll
    for (int mi = 0; mi < 4; mi++)
      af[mi] = *(const f16x8*)&Al[(wr * 64 + mi * 16 + lc) * BK + lg * 8];
#pragma unroll
    for (int nj = 0; nj < 4; nj++)
      bfr[nj] = *(const f16x8*)&Bl[(wc * 64 + nj * 16 + lc) * BK + lg * 8];
#pragma unroll
    for (int mi = 0; mi < 4; mi++)
#pragma unroll
      for (int nj = 0; nj < 4; nj++)
        acc[mi][nj] = __builtin_amdgcn_mfma_f32_16x16x32_f16(af[mi], bfr[nj],
                                                             acc[mi][nj], 0, 0, 0);
  }

  const int np = n0 >> 10;
  u16* outp = np == 0 ? qp : (np == 1 ? kp : vp);
  const float* bias = np == 0 ? bq : (np == 1 ? bk2 : bv);
  const float scale = np == 0 ? (0.125f * LOG2E) : 1.0f;
  const int nc0 = (n0 & 1023) + wc * 64;
  float bvals[4];
#pragma unroll
  for (int nj = 0; nj < 4; nj++) bvals[nj] = bias[nc0 + nj * 16 + lc];
#pragma unroll
  for (int mi = 0; mi < 4; mi++)
#pragma unroll
    for (int nj = 0; nj < 4; nj++)
#pragma unroll
      for (int r = 0; r < 4; r++) {
        int row = m0 + wr * 64 + mi * 16 + lg * 4 + r;
        outp[(size_t)row * 1024 + nc0 + nj * 16 + lc] =
            f2h((acc[mi][nj][r] + bvals[nj]) * scale);
      }
}

// ---------------------------------------------------------------------------
// O-projection, fp16: out = ctx @ Wo^T + bias, fp32 out.
// 128(M)x64(N) tile -> 512 blocks = 2 blocks/CU (r18 committed).
// ---------------------------------------------------------------------------
__global__ __launch_bounds__(256) void gemm_oproj(
    const u16* __restrict__ A16, const u16* __restrict__ B16,
    const float* __restrict__ bias, float* __restrict__ out) {
  __shared__ __align__(16) u16 Al[128 * BK];   // 8KB
  __shared__ __align__(16) u16 Bl[64 * BK];    // 4KB
  const int tid = threadIdx.x;
  const int w = tid >> 6, l = tid & 63, lg = l >> 4, lc = l & 15;
  const int m0 = blockIdx.y * 128, n0 = blockIdx.x * 64;
  const int sra = tid >> 2, sca = (tid & 3) * 8;
  const int srb = (tid >> 2) & 63;

  f32x4 acc[2][4];
#pragma unroll
  for (int i = 0; i < 2; i++)
#pragma unroll
    for (int j = 0; j < 4; j++) acc[i][j] = (f32x4){0.f, 0.f, 0.f, 0.f};

  for (int k0 = 0; k0 < H_DIM; k0 += BK) {
    __syncthreads();
    load_lds16(&A16[(size_t)(m0 + sra) * H_DIM + k0 + sca],      &Al[w * 512]);
    load_lds16(&A16[(size_t)(m0 + 64 + sra) * H_DIM + k0 + sca], &Al[2048 + w * 512]);
    load_lds16(&B16[(size_t)(n0 + srb) * H_DIM + k0 + sca],      &Bl[w * 512]);
    __syncthreads();

    f16x8 af[2], bfr[4];
#pragma unroll
    for (int mi = 0; mi < 2; mi++)
      af[mi] = *(const f16x8*)&Al[(w * 32 + mi * 16 + lc) * BK + lg * 8];
#pragma unroll
    for (int nj = 0; nj < 4; nj++)
      bfr[nj] = *(const f16x8*)&Bl[(nj * 16 + lc) * BK + lg * 8];
#pragma unroll
    for (int mi = 0; mi < 2; mi++)
#pragma unroll
      for (int nj = 0; nj < 4; nj++)
        acc[mi][nj] = __builtin_amdgcn_mfma_f32_16x16x32_f16(af[mi], bfr[nj],
                                                             acc[mi][nj], 0, 0, 0);
  }

  float bvals[4];
#pragma unroll
  for (int nj = 0; nj < 4; nj++) bvals[nj] = bias[n0 + nj * 16 + lc];
#pragma unroll
  for (int mi = 0; mi < 2; mi++)
#pragma unroll
    for (int nj = 0; nj < 4; nj++)
#pragma unroll
      for (int r = 0; r < 4; r++) {
        int row = m0 + w * 32 + mi * 16 + lg * 4 + r;
        out[(size_t)row * 1024 + n0 + nj * 16 + lc] = acc[mi][nj][r] + bvals[nj];
      }
}

// ---------------------------------------------------------------------------
// Flash attention v13: r17/r18 structure (8-wave block, 2 KV halves, in-block
// combine), with the per-tile l-sum computed by a packed-fp16 tree over the
// 16 existing P words (v_pk_add_f16) instead of 32 fp32 adds. l is now the
// sum of the exact RTZ-rounded P values used in PV (consistent ratio).
// ---------------------------------------------------------------------------
#define KTILES 16

__global__ __launch_bounds__(512, 2) void attn_mfma13(
    const u16* __restrict__ q, const u16* __restrict__ k,
    const u16* __restrict__ v, u16* __restrict__ ctx) {
  __shared__ __align__(16) u16 Ks[2][64 * 64];   // 16KB (also ExO in epilogue)
  __shared__ __align__(16) u16 Vt[2][64 * 64];   // 16KB (also ExL in epilogue)

  const int tid = threadIdx.x;
  const int w8 = tid >> 6;            // 0..7
  const int half = w8 >> 2;           // KV half
  const int w = w8 & 3;               // wave within half
  const int l = tid & 63;
  const int l31 = l & 31, l5 = l >> 5;
  const int ht = tid & 255;           // thread within half
  // XCD swizzle (bijective, 512 wgs)
  const int wg = (blockIdx.x & 7) * 64 + (blockIdx.x >> 3);
  const int qt = wg & 15;
  const int h  = (wg >> 4) & 15;
  const int b  = wg >> 8;
  const size_t row0 = (size_t)b * SEQ;
  const int grow = qt * 128 + w * 32 + l31;

  f16x8 qf[4];
  {
    const u16* qp = q + (row0 + grow) * H_DIM + h * HDIM + 8 * l5;
#pragma unroll
    for (int dc = 0; dc < 4; dc++)
      qf[dc] = *(const f16x8*)(qp + dc * 16);
  }

  const int c1 = ht + 256;
  const u16* ksrc0 = k + (row0 + half * 1024 + (ht >> 3)) * H_DIM + h * HDIM
                       + ((ht & 7) ^ ((ht >> 3) & 7)) * 8;
  const u16* ksrc1 = k + (row0 + half * 1024 + (c1 >> 3)) * H_DIM + h * HDIM
                       + ((c1 & 7) ^ ((c1 >> 3) & 7)) * 8;

  const int vd = ht & 63, ko = ht >> 6;
  const u16* vsrc = v + (row0 + half * 1024 + ko * 8) * H_DIM + h * HDIM + vd;
  const int vwo0 = vd * 64 + ((ko)     ^ (vd & 7)) * 8;
  const int vwo1 = vd * 64 + ((ko + 4) ^ (vd & 7)) * 8;

  uint4 rV0, rV1;
  {
    unsigned a0 = vsrc[0 * H_DIM], a1 = vsrc[1 * H_DIM];
    unsigned a2 = vsrc[2 * H_DIM], a3 = vsrc[3 * H_DIM];
    unsigned a4 = vsrc[4 * H_DIM], a5 = vsrc[5 * H_DIM];
    unsigned a6 = vsrc[6 * H_DIM], a7 = vsrc[7 * H_DIM];
    rV0.x = a0 | (a1 << 16); rV0.y = a2 | (a3 << 16);
    rV0.z = a4 | (a5 << 16); rV0.w = a6 | (a7 << 16);
    const u16* v2 = vsrc + 32 * H_DIM;
    unsigned b0 = v2[0 * H_DIM], b1 = v2[1 * H_DIM];
    unsigned b2 = v2[2 * H_DIM], b3 = v2[3 * H_DIM];
    unsigned b4 = v2[4 * H_DIM], b5 = v2[5 * H_DIM];
    unsigned b6 = v2[6 * H_DIM], b7 = v2[7 * H_DIM];
    rV1.x = b0 | (b1 << 16); rV1.y = b2 | (b3 << 16);
    rV1.z = b4 | (b5 << 16); rV1.w = b6 | (b7 << 16);
  }

  f32x16 Oacc[2];
#pragma unroll
  for (int i = 0; i < 2; i++)
#pragma unroll
    for (int r = 0; r < 16; r++) Oacc[i][r] = 0.f;
  float lS = 0.f;

  for (int t = 0; t < KTILES; ++t) {
    __syncthreads();
    load_lds16(ksrc0, &Ks[half][w * 512]);
    load_lds16(ksrc1, &Ks[half][2048 + w * 512]);
    *(uint4*)&Vt[half][vwo0] = rV0;
    *(uint4*)&Vt[half][vwo1] = rV1;
    __syncthreads();
    ksrc0 += 64 * H_DIM;
    ksrc1 += 64 * H_DIM;

    if (t + 1 < KTILES) {
      vsrc += 64 * H_DIM;
      unsigned a0 = vsrc[0 * H_DIM], a1 = vsrc[1 * H_DIM];
      unsigned a2 = vsrc[2 * H_DIM], a3 = vsrc[3 * H_DIM];
      unsigned a4 = vsrc[4 * H_DIM], a5 = vsrc[5 * H_DIM];
      unsigned a6 = vsrc[6 * H_DIM], a7 = vsrc[7 * H_DIM];
      rV0.x = a0 | (a1 << 16); rV0.y = a2 | (a3 << 16);
      rV0.z = a4 | (a5 << 16); rV0.w = a6 | (a7 << 16);
      const u16* v2 = vsrc + 32 * H_DIM;
      unsigned b0 = v2[0 * H_DIM], b1 = v2[1 * H_DIM];
      unsigned b2 = v2[2 * H_DIM], b3 = v2[3 * H_DIM];
      unsigned b4 = v2[4 * H_DIM], b5 = v2[5 * H_DIM];
      unsigned b6 = v2[6 * H_DIM], b7 = v2[7 * H_DIM];
      rV1.x = b0 | (b1 << 16); rV1.y = b2 | (b3 << 16);
      rV1.z = b4 | (b5 << 16); rV1.w = b6 | (b7 << 16);
    }

    // ---- QK + exp + pack ----
    unsigned pw[2][4][2];
#pragma unroll
    for (int kc = 0; kc < 2; kc++) {
      f32x16 s;
#pragma unroll
      for (int r = 0; r < 16; r++) s[r] = 0.f;
      const int key = kc * 32 + l31;
      const int rowb = key * 64, keyx = key & 7;
#pragma unroll
      for (int dc = 0; dc < 4; dc++) {
        f16x8 af = *(const f16x8*)&Ks[half][rowb + (((dc << 1) + l5) ^ keyx) * 8];
        s = __builtin_amdgcn_mfma_f32_32x32x16_f16(af, qf[dc], s, 0, 0, 0);
      }
#pragma unroll
      for (int rh = 0; rh < 4; rh++)
#pragma unroll
        for (int k1 = 0; k1 < 2; k1++) {
          float e0 = exp2f(s[4 * rh + 2 * k1]);
          float e1 = exp2f(s[4 * rh + 2 * k1 + 1]);
          pw[kc][rh][k1] = __builtin_bit_cast(
              unsigned, __builtin_amdgcn_cvt_pkrtz(e0, e1));
        }
    }
    // ---- l-sum: packed-fp16 tree over the 16 P words (v_pk_add_f16) ----
    {
      f16x2 t0 = (bch(pw[0][0][0]) + bch(pw[0][0][1])) +
                 (bch(pw[0][1][0]) + bch(pw[0][1][1]));
      f16x2 t1 = (bch(pw[0][2][0]) + bch(pw[0][2][1])) +
                 (bch(pw[0][3][0]) + bch(pw[0][3][1]));
      f16x2 t2 = (bch(pw[1][0][0]) + bch(pw[1][0][1])) +
                 (bch(pw[1][1][0]) + bch(pw[1][1][1]));
      f16x2 t3 = (bch(pw[1][2][0]) + bch(pw[1][2][1])) +
                 (bch(pw[1][3][0]) + bch(pw[1][3][1]));
      f16x2 tt = (t0 + t1) + (t2 + t3);
      lS += (float)tt[0] + (float)tt[1];
    }

    // ---- PV: B-frags via permlane32_swap, A-frags from Vt ----
#pragma unroll
    for (int kcc = 0; kcc < 4; kcc++) {
      union { unsigned u[4]; f16x8 v8; } bf;
      const int kcs = kcc >> 1, rhA = (kcc & 1) << 1;
#pragma unroll
      for (int k1 = 0; k1 < 2; k1++) {
        uint2v xy = __builtin_amdgcn_permlane32_swap(
            pw[kcs][rhA][k1], pw[kcs][rhA + 1][k1], false, false);
        bf.u[k1] = xy.x;
        bf.u[2 + k1] = xy.y;
      }
#pragma unroll
      for (int dc2 = 0; dc2 < 2; dc2++) {
        const int d = dc2 * 32 + l31;
        f16x8 vf = *(const f16x8*)&Vt[half][d * 64 + (((kcc << 1) + l5) ^ (d & 7)) * 8];
        Oacc[dc2] = __builtin_amdgcn_mfma_f32_32x32x16_f16(vf, bf.v8,
                                                           Oacc[dc2], 0, 0, 0);
      }
    }
  }

  // ---- epilogue: in-block combine of the two halves ----
  __syncthreads();
  lS += __shfl_xor(lS, 32);
  const int qloc = w * 32 + l31;
  u16* ExO = &Ks[0][0];
  float* ExL = (float*)&Vt[0][0];

  if (half == 1) {
#pragma unroll
    for (int dc2 = 0; dc2 < 2; dc2++)
#pragma unroll
      for (int rh = 0; rh < 4; rh++) {
        uint2 pd;
        pd.x = __builtin_bit_cast(unsigned, __builtin_amdgcn_cvt_pkrtz(
            Oacc[dc2][4 * rh + 0], Oacc[dc2][4 * rh + 1]));
        pd.y = __builtin_bit_cast(unsigned, __builtin_amdgcn_cvt_pkrtz(
            Oacc[dc2][4 * rh + 2], Oacc[dc2][4 * rh + 3]));
        const int chunk = dc2 * 4 + rh;
        *(uint2*)&ExO[qloc * 64 + ((chunk ^ (qloc & 7)) << 3) + 4 * l5] = pd;
      }
    if (l < 32) ExL[qloc] = lS;
  }
  __syncthreads();
  if (half == 0) {
    float inv = 1.f / (lS + ExL[qloc]);
    const size_t obase = (row0 + grow) * H_DIM + h * HDIM;
#pragma unroll
    for (int dc2 = 0; dc2 < 2; dc2++)
#pragma unroll
      for (int rh = 0; rh < 4; rh++) {
        const int chunk = dc2 * 4 + rh;
        uint2 t = *(const uint2*)&ExO[qloc * 64 + ((chunk ^ (qloc & 7)) << 3) + 4 * l5];
        float o0 = (Oacc[dc2][4 * rh + 0] + h2f(t.x)) * inv;
        float o1 = (Oacc[dc2][4 * rh + 1] + h2f(t.x >> 16)) * inv;
        float o2 = (Oacc[dc2][4 * rh + 2] + h2f(t.y)) * inv;
        float o3 = (Oacc[dc2][4 * rh + 3] + h2f(t.y >> 16)) * inv;
        uint2 pd;
        pd.x = __builtin_bit_cast(unsigned, __builtin_amdgcn_cvt_pkrtz(o0, o1));
        pd.y = __builtin_bit_cast(unsigned, __builtin_amdgcn_cvt_pkrtz(o2, o3));
        *(uint2*)&ctx[obase + dc2 * 32 + 8 * rh + 4 * l5] = pd;
      }
  }
}

// ---------------------------------------------------------------------------
extern "C" void kernel_launch(void* const* d_in, const int* in_sizes, int n_in,
                              void* d_out, int out_size, void* d_ws, size_t ws_size,
                              hipStream_t stream) {
  const float* x  = (const float*)d_in[0];
  const float* Wq = (const float*)d_in[1];
  const float* bq = (const float*)d_in[2];
  const float* Wk = (const float*)d_in[3];
  const float* bk = (const float*)d_in[4];
  const float* Wv = (const float*)d_in[5];
  const float* bv = (const float*)d_in[6];
  const float* Wo = (const float*)d_in[7];
  const float* bo = (const float*)d_in[8];
  float* out = (float*)d_out;

  const size_t PL = (size_t)MTOT * H_DIM;   // 4M elems
  const size_t WN = (size_t)H_DIM * H_DIM;  // 1M elems
  u16* xb    = (u16*)d_ws;                  // fp16 planes
  u16* W3    = xb + PL;
  u16* qp    = W3 + 3 * WN;
  u16* kp    = qp + PL;
  u16* vp    = kp + PL;
  u16* ctxp  = vp + PL;
  u16* Wo16  = ctxp + PL;

  conv_all<<<(N8X + 4 * N8W) / 256, 256, 0, stream>>>(
      x, Wq, Wk, Wv, Wo, xb, W3, Wo16);

  gemm_qkv<<<dim3(3072 / 128, MTOT / 128), 256, 0, stream>>>(
      xb, W3, bq, bk, bv, qp, kp, vp);

  attn_mfma13<<<dim3(512), 512, 0, stream>>>(qp, kp, vp, ctxp);

  gemm_oproj<<<dim3(1024 / 64, MTOT / 128), 256, 0, stream>>>(
      ctxp, Wo16, bo, out);
}